// Round 17
// baseline (264.256 us; speedup 1.0000x reference)
//
#include <hip/hip_runtime.h>
#include <math.h>

// CausalSelfAttention: B=4 T=2048 C=1024 H=16 hd=64. fp32 I/O, bf16 MFMA internals.
// R16 = R15-exact (passed, 199.1us) + ONE change: gemm_qkv BN 128->256.
//   A-staging (f32 loads + f2b conversion + LDS protocol) byte-identical to the
//   proven R6 form; only B-copy doubled (b2,b3) and per-wave N-fragments doubled
//   (bfr[8], acc[4][8], 32 MFMA/k-step). Conversion-VALU per MFMA halves.
//   Epilogue = R6 body looped over 2 head-groups (identical per-element ops).
//
// ws (u16 elems), peak 33,554,432 u16 = 64 MiB:
//   [0,        8388608)  Qg          ... after attn: WpT over dead Qg
//   [8388608, 16777216)  Kg
//   [16777216,25165824)  Vg          ... after V-transpose: Yb over dead Vg
//   [25165824,28311552)  WaT (bf16)  ... dead after QKV GEMM
//   [28311552,28442624)  rope tab    ... dead after QKV GEMM
//   [25165824,33554432)  VgT (over dead WaT+tab)

typedef unsigned short u16;
typedef __bf16 bf16x8 __attribute__((ext_vector_type(8)));
typedef float f32x4 __attribute__((ext_vector_type(4)));
typedef float f32x16 __attribute__((ext_vector_type(16)));

#define QSCALE 0.18033688501389543f  // 0.125 * log2(e)

__device__ __forceinline__ float b2f(u16 x) {
  union { unsigned u; float f; } c; c.u = ((unsigned)x) << 16; return c.f;
}
__device__ __forceinline__ u16 f2b(float f) {
  union { __bf16 h; u16 u; } c; c.h = (__bf16)f; return c.u;
}

#define GLOAD16(gp, lp)                                                  \
  __builtin_amdgcn_global_load_lds(                                      \
      (const __attribute__((address_space(1))) unsigned int*)(gp),       \
      (__attribute__((address_space(3))) unsigned int*)(lp), 16, 0, 0)

// ---------------- sentinel fill (ws too small signal)
__global__ __launch_bounds__(256) void sentinel_k(u16* __restrict__ out, int n) {
  int i = blockIdx.x * 256 + threadIdx.x;
  if (i < n) out[i] = 0x4480;  // bf16 1024.0
}

// ---------------- transpose fp32 src[R][C] -> bf16 dst[C][R], 64x64 tiles
__global__ __launch_bounds__(256) void transpose_f2b_k(const float* __restrict__ src,
                                                       u16* __restrict__ dst,
                                                       int R, int C) {
  __shared__ u16 tile[64][65];
  int tc = blockIdx.x * 64, tr = blockIdx.y * 64;
  int t = threadIdx.x;
  int rr = t >> 3;
  int c8 = (t & 7) * 8;
#pragma unroll
  for (int i = 0; i < 2; ++i) {
    int r = rr + i * 32;
    f32x4 p0 = *(const f32x4*)(src + (long)(tr + r) * C + tc + c8);
    f32x4 p1 = *(const f32x4*)(src + (long)(tr + r) * C + tc + c8 + 4);
#pragma unroll
    for (int j = 0; j < 4; ++j) {
      tile[r][c8 + j] = f2b(p0[j]);
      tile[r][c8 + 4 + j] = f2b(p1[j]);
    }
  }
  __syncthreads();
#pragma unroll
  for (int i = 0; i < 2; ++i) {
    int a = rr + i * 32;
    u16 vv[8];
#pragma unroll
    for (int j = 0; j < 8; ++j) vv[j] = tile[c8 + j][a];
    *(uint4*)(dst + (long)(tc + a) * R + tr + c8) = *(uint4*)vv;
  }
}

// ---------------- transpose bf16 src[R][C] -> bf16 dst[C][R], batched via z
__global__ __launch_bounds__(256) void transpose_b_k(const u16* __restrict__ src,
                                                     u16* __restrict__ dst,
                                                     int R, int C,
                                                     long sBatch, long dBatch) {
  __shared__ u16 tile[64][65];
  src += (long)blockIdx.z * sBatch;
  dst += (long)blockIdx.z * dBatch;
  int tc = blockIdx.x * 64, tr = blockIdx.y * 64;
  int t = threadIdx.x;
  int rr = t >> 3;
  int c8 = (t & 7) * 8;
#pragma unroll
  for (int i = 0; i < 2; ++i) {
    int r = rr + i * 32;
    uint4 v = *(const uint4*)(src + (long)(tr + r) * C + tc + c8);
    u16 vv[8]; *(uint4*)vv = v;
#pragma unroll
    for (int j = 0; j < 8; ++j) tile[r][c8 + j] = vv[j];
  }
  __syncthreads();
#pragma unroll
  for (int i = 0; i < 2; ++i) {
    int a = rr + i * 32;
    u16 vv[8];
#pragma unroll
    for (int j = 0; j < 8; ++j) vv[j] = tile[c8 + j][a];
    *(uint4*)(dst + (long)(tc + a) * R + tr + c8) = *(uint4*)vv;
  }
}

// ---------------- rope table: [2048][16] float2(cos,sin)
__global__ void rope_table_k(float2* __restrict__ tab) {
  int i = blockIdx.x * 256 + threadIdx.x;
  if (i >= 2048 * 16) return;
  int t = i >> 4, f = i & 15;
  float invf = exp2f(-(float)f * (13.287712379549449f / 16.0f));
  float th = (float)t * invf;
  float s, c;
  sincosf(th, &s, &c);
  tab[i] = make_float2(c, s);
}

// ---------------- QKV GEMM: qkv = x @ WaT^T + ba, RoPE fused in epilogue.
// R6 staging protocol; BN=256 (B-copy doubled, A-side identical).
__global__ __launch_bounds__(256) void gemm_qkv_k(const float* __restrict__ A,
                                                  const u16* __restrict__ Bt,
                                                  const float* __restrict__ bias,
                                                  const float2* __restrict__ tab,
                                                  u16* __restrict__ out,
                                                  int M, int N, int K) {
  __shared__ u16 As[128 * 40];
  __shared__ u16 Bs[256 * 40];
  int tid = threadIdx.x, wid = tid >> 6, lane = tid & 63;
  int wr = wid >> 1, wc = wid & 1;
  long m0 = (long)blockIdx.x * 128, n0 = (long)blockIdx.y * 256;
  int r = lane & 15, g = lane >> 4;
  long arow = m0 + wid * 32 + (lane >> 2);
  int acol = (lane & 3) * 8;
  const float* Agf = A + arow * (long)K + acol;
  const u16* Bg = Bt + (n0 + wid * 32 + (lane >> 2)) * (long)K + acol;
  int lrow = wid * 32 + (lane >> 2);
  int lcol = acol;
  f32x4 acc[4][8] = {};
  int nk = K >> 5;
  for (int kt = 0; kt < nk; ++kt) {
    long ko = (long)kt * 32;
    f32x4 p0 = *(const f32x4*)(Agf + ko);
    f32x4 p1 = *(const f32x4*)(Agf + ko + 4);
    f32x4 p2 = *(const f32x4*)(Agf + ko + 16 * (long)K);
    f32x4 p3 = *(const f32x4*)(Agf + ko + 16 * (long)K + 4);
    u16 h0[8], h1[8];
#pragma unroll
    for (int j = 0; j < 4; ++j) {
      h0[j] = f2b(p0[j]); h0[4 + j] = f2b(p1[j]);
      h1[j] = f2b(p2[j]); h1[4 + j] = f2b(p3[j]);
    }
    uint4 a0 = *(uint4*)h0, a1 = *(uint4*)h1;
    uint4 b0 = *(const uint4*)(Bg + ko);
    uint4 b1 = *(const uint4*)(Bg + ko + 16 * (long)K);
    uint4 b2 = *(const uint4*)(Bg + ko + 128 * (long)K);
    uint4 b3 = *(const uint4*)(Bg + ko + 144 * (long)K);
    __syncthreads();
    *(uint4*)&As[lrow * 40 + lcol] = a0;
    *(uint4*)&As[(lrow + 16) * 40 + lcol] = a1;
    *(uint4*)&Bs[lrow * 40 + lcol] = b0;
    *(uint4*)&Bs[(lrow + 16) * 40 + lcol] = b1;
    *(uint4*)&Bs[(lrow + 128) * 40 + lcol] = b2;
    *(uint4*)&Bs[(lrow + 144) * 40 + lcol] = b3;
    __syncthreads();
    bf16x8 af[4], bfr[8];
#pragma unroll
    for (int mt = 0; mt < 4; ++mt)
      af[mt] = *(const bf16x8*)&As[(wr * 64 + mt * 16 + r) * 40 + g * 8];
#pragma unroll
    for (int nt = 0; nt < 8; ++nt)
      bfr[nt] = *(const bf16x8*)&Bs[(wc * 128 + nt * 16 + r) * 40 + g * 8];
#pragma unroll
    for (int mt = 0; mt < 4; ++mt)
#pragma unroll
      for (int nt = 0; nt < 8; ++nt)
        acc[mt][nt] = __builtin_amdgcn_mfma_f32_16x16x32_bf16(af[mt], bfr[nt], acc[mt][nt], 0, 0, 0);
  }
  int which = (int)(n0 >> 10);  // 256-wide tiles never straddle q/k/v (1024%256==0)
  int hhb = ((int)(n0 & 1023) >> 6) + wc * 2;
#pragma unroll
  for (int hg = 0; hg < 2; ++hg) {
    int hh = hhb + hg;
    float bv[4];
#pragma unroll
    for (int j = 0; j < 4; ++j) bv[j] = bias[n0 + wc * 128 + hg * 64 + j * 16 + r];
#pragma unroll
    for (int mt = 0; mt < 4; ++mt) {
#pragma unroll
      for (int e = 0; e < 4; ++e) {
        long row = m0 + wr * 64 + mt * 16 + g * 4 + e;
        long bb = row >> 11;
        int tt = (int)row & 2047;
        float v0 = acc[mt][hg * 4 + 0][e] + bv[0];
        float v1 = acc[mt][hg * 4 + 1][e] + bv[1];
        float v2 = acc[mt][hg * 4 + 2][e] + bv[2];
        float v3 = acc[mt][hg * 4 + 3][e] + bv[3];
        if (which < 2) {
          float2 cs = tab[tt * 16 + r];
          float r0 = v0 * cs.x - v2 * cs.y, r2 = v2 * cs.x + v0 * cs.y;
          float r1 = v1 * cs.x - v3 * cs.y, r3 = v3 * cs.x + v1 * cs.y;
          if (which == 0) { r0 *= QSCALE; r1 *= QSCALE; r2 *= QSCALE; r3 *= QSCALE; }
          v0 = r0; v1 = r1; v2 = r2; v3 = r3;
        }
        u16* op = out + (long)which * 8388608 + (((bb * 16 + hh) * 2048 + tt) << 6);
        op[r] = f2b(v0);
        op[16 + r] = f2b(v1);
        op[32 + r] = f2b(v2);
        op[48 + r] = f2b(v3);
      }
    }
  }
}

// ---------------- proj GEMM: out = A @ Bt^T + bias, global_load_lds staging.
__global__ __launch_bounds__(256) void gemm_proj_k(const u16* __restrict__ A,
                                                   const u16* __restrict__ Bt,
                                                   const float* __restrict__ bias,
                                                   float* __restrict__ out,
                                                   int M, int N, int K) {
  __shared__ u16 As[128 * 32];
  __shared__ u16 Bs[128 * 32];
  int tid = threadIdx.x, wid = tid >> 6, lane = tid & 63;
  int wr = wid >> 1, wc = wid & 1;
  long m0 = (long)blockIdx.x * 128, n0 = (long)blockIdx.y * 128;
  int r = lane & 15, g = lane >> 4;
  const u16* Ag = A + (m0 + wid * 32 + (lane >> 2)) * (long)K + (lane & 3) * 8;
  const u16* Bg = Bt + (n0 + wid * 32 + (lane >> 2)) * (long)K + (lane & 3) * 8;
  u16* AsW = As + wid * 1024;
  u16* BsW = Bs + wid * 1024;
  f32x4 acc[4][4] = {};
  int nk = K >> 5;
  for (int kt = 0; kt < nk; ++kt) {
    long ko = (long)kt * 32;
    GLOAD16(Ag + ko, AsW);
    GLOAD16(Ag + ko + 16 * (long)K, AsW + 512);
    GLOAD16(Bg + ko, BsW);
    GLOAD16(Bg + ko + 16 * (long)K, BsW + 512);
    __syncthreads();
    bf16x8 af[4], bfr[4];
#pragma unroll
    for (int mt = 0; mt < 4; ++mt)
      af[mt] = *(const bf16x8*)&As[(wr * 64 + mt * 16 + r) * 32 + g * 8];
#pragma unroll
    for (int nt = 0; nt < 4; ++nt)
      bfr[nt] = *(const bf16x8*)&Bs[(wc * 64 + nt * 16 + r) * 32 + g * 8];
#pragma unroll
    for (int mt = 0; mt < 4; ++mt)
#pragma unroll
      for (int nt = 0; nt < 4; ++nt)
        acc[mt][nt] = __builtin_amdgcn_mfma_f32_16x16x32_bf16(af[mt], bfr[nt], acc[mt][nt], 0, 0, 0);
    __syncthreads();
  }
#pragma unroll
  for (int nt = 0; nt < 4; ++nt) {
    long col = n0 + wc * 64 + nt * 16 + r;
    float bvv = bias[col];
#pragma unroll
    for (int mt = 0; mt < 4; ++mt)
#pragma unroll
      for (int e = 0; e < 4; ++e) {
        long row = m0 + wr * 64 + mt * 16 + g * 4 + e;
        out[row * N + col] = acc[mt][nt][e] + bvv;
      }
  }
}

// ======== attn helpers ========
__device__ __forceinline__ void pk_exchange(const f32x16& p, bf16x8& af0, bf16x8& af1) {
  unsigned w0, w1, w2, w3, w4, w5, w6, w7;
  asm("v_cvt_pk_bf16_f32 %0, %1, %2" : "=v"(w0) : "v"(p[0]), "v"(p[1]));
  asm("v_cvt_pk_bf16_f32 %0, %1, %2" : "=v"(w1) : "v"(p[2]), "v"(p[3]));
  asm("v_cvt_pk_bf16_f32 %0, %1, %2" : "=v"(w2) : "v"(p[4]), "v"(p[5]));
  asm("v_cvt_pk_bf16_f32 %0, %1, %2" : "=v"(w3) : "v"(p[6]), "v"(p[7]));
  asm("v_cvt_pk_bf16_f32 %0, %1, %2" : "=v"(w4) : "v"(p[8]), "v"(p[9]));
  asm("v_cvt_pk_bf16_f32 %0, %1, %2" : "=v"(w5) : "v"(p[10]), "v"(p[11]));
  asm("v_cvt_pk_bf16_f32 %0, %1, %2" : "=v"(w6) : "v"(p[12]), "v"(p[13]));
  asm("v_cvt_pk_bf16_f32 %0, %1, %2" : "=v"(w7) : "v"(p[14]), "v"(p[15]));
  asm("v_permlane32_swap_b32 %0, %1" : "+v"(w0), "+v"(w2));
  asm("v_permlane32_swap_b32 %0, %1" : "+v"(w1), "+v"(w3));
  asm("v_permlane32_swap_b32 %0, %1" : "+v"(w4), "+v"(w6));
  asm("v_permlane32_swap_b32 %0, %1" : "+v"(w5), "+v"(w7));
  union { unsigned u[4]; bf16x8 v; } c0, c1;
  c0.u[0] = w0; c0.u[1] = w1; c0.u[2] = w2; c0.u[3] = w3;
  c1.u[0] = w4; c1.u[1] = w5; c1.u[2] = w6; c1.u[3] = w7;
  af0 = c0.v;
  af1 = c1.v;
}

// ---------------- flash attention v9: 8-wave blocks, q-span 256, KVBLK=64.
// Same staged tile feeds 8 waves; qmap balances work across block pairs.
// Single-buffer two-barrier skeleton + hoisted loads (R12-proven protocol).
__global__ __launch_bounds__(512) void attn_k(const u16* __restrict__ Qg,
                                              const u16* __restrict__ Kg,
                                              const u16* __restrict__ VgT,
                                              u16* __restrict__ Y) {
  __shared__ u16 Ks[64 * 72];  // [kv 64][d 64] +8 pad
  __shared__ u16 Vt[64 * 72];  // [d 64][kv 64] +8 pad
  const int qmap[8] = {7, 5, 6, 4, 0, 2, 1, 3};  // pairs (y, y+4) sum to 7
  int qb = qmap[blockIdx.y];
  int bh = blockIdx.x;
  int b = bh >> 4, h = bh & 15;
  long base = (long)bh * (2048 * 64);
  int tid = threadIdx.x, wid = tid >> 6;       // 0..7
  int lane = tid & 63, l31 = lane & 31, hi = lane >> 5;
  int q0 = qb * 256 + wid * 32;
  int endS = (q0 + 31) >> 6;    // last kv tile for this wave
  int ktMax = 4 * qb + 3;       // block max (wave 7)
  // staging: 512 threads x 1 uint4 = 64x64 u16 per array
  int srow = tid >> 3, sch = (tid & 7) * 8;
  const u16* kSrc = Kg + base + (long)srow * 64 + sch;     // +kt*4096
  const u16* vSrc = VgT + base + (long)srow * 2048 + sch;  // +kt*64
  int sOff = srow * 72 + sch;
  bf16x8 qf[4];
  {
    const u16* qp = Qg + base + (long)(q0 + l31) * 64 + hi * 8;
#pragma unroll
    for (int s4 = 0; s4 < 4; ++s4) qf[s4] = *(const bf16x8*)(qp + s4 * 16);
  }
  f32x16 acc0 = {}, acc1 = {};
  float mrow = -INFINITY, lrow = 0.f;
  // prologue: tile-0 loads in flight
  uint4 rk = *(const uint4*)kSrc;
  uint4 rv = *(const uint4*)vSrc;
  for (int kt = 0; kt <= ktMax; ++kt) {
    __syncthreads();            // all waves done reading tile kt-1
    *(uint4*)&Ks[sOff] = rk;
    *(uint4*)&Vt[sOff] = rv;
    __syncthreads();            // tile kt visible
    if (kt < ktMax) {           // hoist tile kt+1 loads under this compute
      rk = *(const uint4*)(kSrc + (long)(kt + 1) * 4096);
      rv = *(const uint4*)(vSrc + (long)(kt + 1) * 64);
    }
    if (kt > endS) continue;    // wave done with its strip (still hits barriers)
    f32x16 st[2];
    __builtin_amdgcn_s_setprio(1);
#pragma unroll
    for (int ct = 0; ct < 2; ++ct) {
      f32x16 z = {};
#pragma unroll
      for (int s4 = 0; s4 < 4; ++s4) {
        bf16x8 kf = *(const bf16x8*)&Ks[(ct * 32 + l31) * 72 + s4 * 16 + hi * 8];
        z = __builtin_amdgcn_mfma_f32_32x32x16_bf16(kf, qf[s4], z, 0, 0, 0);
      }
      st[ct] = z;
    }
    __builtin_amdgcn_s_setprio(0);
    if (kt == endS) {  // causal mask on diagonal tile
      int qg = q0 + l31;
#pragma unroll
      for (int ct = 0; ct < 2; ++ct)
#pragma unroll
        for (int reg = 0; reg < 16; ++reg) {
          int kg = kt * 64 + ct * 32 + (reg & 3) + 8 * (reg >> 2) + 4 * hi;
          if (kg > qg) st[ct][reg] = -INFINITY;
        }
    }
    float t8[8];
#pragma unroll
    for (int i = 0; i < 8; ++i)
      t8[i] = fmaxf(fmaxf(st[0][i], st[0][i + 8]), fmaxf(st[1][i], st[1][i + 8]));
#pragma unroll
    for (int i = 0; i < 4; ++i) t8[i] = fmaxf(t8[i], t8[i + 4]);
    float pm = fmaxf(fmaxf(t8[0], t8[1]), fmaxf(t8[2], t8[3]));
    pm = fmaxf(pm, __shfl_xor(pm, 32));
    if (__any(pm > mrow + 8.0f)) {  // defer-max (T13)
      float mn = fmaxf(mrow, pm);
      float alpha = exp2f(mrow - mn);
      mrow = mn;
      lrow *= alpha;
#pragma unroll
      for (int reg = 0; reg < 16; ++reg) {
        float aB = __shfl(alpha, (reg & 3) + 8 * (reg >> 2) + 4 * hi);
        acc0[reg] *= aB;
        acc1[reg] *= aB;
      }
    }
    float s8[8];
#pragma unroll
    for (int i = 0; i < 8; ++i) s8[i] = 0.f;
#pragma unroll
    for (int ct = 0; ct < 2; ++ct)
#pragma unroll
      for (int reg = 0; reg < 16; ++reg) {
        float p = exp2f(st[ct][reg] - mrow);
        st[ct][reg] = p;
        s8[reg & 7] += p;
      }
#pragma unroll
    for (int i = 0; i < 4; ++i) s8[i] += s8[i + 4];
    float rs = (s8[0] + s8[1]) + (s8[2] + s8[3]);
    rs += __shfl_xor(rs, 32);
    lrow += rs;
#pragma unroll
    for (int ct = 0; ct < 2; ++ct) {
      bf16x8 af[2];
      pk_exchange(st[ct], af[0], af[1]);
      __builtin_amdgcn_s_setprio(1);
#pragma unroll
      for (int ks = 0; ks < 2; ++ks) {
        bf16x8 vf0 = *(const bf16x8*)&Vt[l31 * 72 + ct * 32 + ks * 16 + hi * 8];
        bf16x8 vf1 = *(const bf16x8*)&Vt[(32 + l31) * 72 + ct * 32 + ks * 16 + hi * 8];
        acc0 = __builtin_amdgcn_mfma_f32_32x32x16_bf16(af[ks], vf0, acc0, 0, 0, 0);
        acc1 = __builtin_amdgcn_mfma_f32_32x32x16_bf16(af[ks], vf1, acc1, 0, 0, 0);
      }
      __builtin_amdgcn_s_setprio(0);
    }
  }
  float rinv = 1.0f / lrow;
#pragma unroll
  for (int reg = 0; reg < 16; ++reg) {
    int crow = (reg & 3) + 8 * (reg >> 2) + 4 * hi;
    float rB = __shfl(rinv, crow);
    long orow = (long)(b * 2048 + q0 + crow) * 1024 + h * 64;
    Y[orow + l31] = f2b(acc0[reg] * rB);
    Y[orow + 32 + l31] = f2b(acc1[reg] * rB);
  }
}

extern "C" void kernel_launch(void* const* d_in, const int* in_sizes, int n_in,
                              void* d_out, int out_size, void* d_ws, size_t ws_size,
                              hipStream_t stream) {
  const float* x  = (const float*)d_in[0];
  const float* Wa = (const float*)d_in[1];
  const float* ba = (const float*)d_in[2];
  const float* Wp = (const float*)d_in[3];
  const float* bp = (const float*)d_in[4];

  if (ws_size < 67108864ULL) {
    sentinel_k<<<dim3((out_size + 255) / 256), 256, 0, stream>>>((u16*)d_out, out_size);
    return;
  }

  u16* ws  = (u16*)d_ws;
  u16* Qg  = ws;                           // [0, 8388608)
  u16* Kg  = ws + 8388608;                 // [8388608, 16777216)
  u16* Vg  = ws + 16777216;                // [16777216, 25165824)
  u16* Yb  = ws + 16777216;                // over dead Vg (after V-transpose)
  u16* WaT = ws + 25165824;                // bf16, dead after QKV GEMM
  float2* tab = (float2*)(ws + 28311552);  // dead after QKV GEMM
  u16* VgT = ws + 25165824;                // over dead WaT+tab
  u16* WpT = ws;                           // over dead Qg (after attn)

  transpose_f2b_k<<<dim3(48, 16), 256, 0, stream>>>(Wa, WaT, 1024, 3072);
  rope_table_k<<<dim3(128), 256, 0, stream>>>(tab);
  gemm_qkv_k<<<dim3(64, 12), 256, 0, stream>>>(x, WaT, ba, tab, Qg, 8192, 3072, 1024);
  transpose_b_k<<<dim3(1, 32, 64), 256, 0, stream>>>(Vg, VgT, 2048, 64, 131072L, 131072L);
  attn_k<<<dim3(64, 8), 512, 0, stream>>>(Qg, Kg, VgT, Yb);
  transpose_f2b_k<<<dim3(16, 16), 256, 0, stream>>>(Wp, WpT, 1024, 1024);
  gemm_proj_k<<<dim3(64, 8), 256, 0, stream>>>(Yb, WpT, bp, (float*)d_out, 8192, 1024, 1024);
}

// Round 18
// 217.672 us; speedup vs baseline: 1.2140x; 1.2140x over previous
//
#include <hip/hip_runtime.h>
#include <math.h>

// CausalSelfAttention: B=4 T=2048 C=1024 H=16 hd=64. fp32 I/O, bf16 MFMA internals.
// R17 = R15-exact (passed, 199.1us; R16's BN=256 qkv reverted) + ONE change:
//   attn KVBLK 64->128: same 8-wave / R12-proven barrier protocol, 2 kv sub-tiles
//   per barrier pair (barrier count halves). Staging regs 2->4 uint4; LDS 35KB.
//   Per-tile math byte-identical.
// gemm_qkv FROZEN at R6 staging (gload_lds variants convicted R13/R14; BN256 slow).
//
// ws (u16 elems), peak 33,554,432 u16 = 64 MiB:
//   [0,        8388608)  Qg          ... after attn: WpT over dead Qg
//   [8388608, 16777216)  Kg
//   [16777216,25165824)  Vg          ... after V-transpose: Yb over dead Vg
//   [25165824,28311552)  WaT (bf16)  ... dead after QKV GEMM
//   [28311552,28442624)  rope tab    ... dead after QKV GEMM
//   [25165824,33554432)  VgT (over dead WaT+tab)

typedef unsigned short u16;
typedef __bf16 bf16x8 __attribute__((ext_vector_type(8)));
typedef float f32x4 __attribute__((ext_vector_type(4)));
typedef float f32x16 __attribute__((ext_vector_type(16)));

#define QSCALE 0.18033688501389543f  // 0.125 * log2(e)

__device__ __forceinline__ float b2f(u16 x) {
  union { unsigned u; float f; } c; c.u = ((unsigned)x) << 16; return c.f;
}
__device__ __forceinline__ u16 f2b(float f) {
  union { __bf16 h; u16 u; } c; c.h = (__bf16)f; return c.u;
}

#define GLOAD16(gp, lp)                                                  \
  __builtin_amdgcn_global_load_lds(                                      \
      (const __attribute__((address_space(1))) unsigned int*)(gp),       \
      (__attribute__((address_space(3))) unsigned int*)(lp), 16, 0, 0)

// ---------------- sentinel fill (ws too small signal)
__global__ __launch_bounds__(256) void sentinel_k(u16* __restrict__ out, int n) {
  int i = blockIdx.x * 256 + threadIdx.x;
  if (i < n) out[i] = 0x4480;  // bf16 1024.0
}

// ---------------- transpose fp32 src[R][C] -> bf16 dst[C][R], 64x64 tiles
__global__ __launch_bounds__(256) void transpose_f2b_k(const float* __restrict__ src,
                                                       u16* __restrict__ dst,
                                                       int R, int C) {
  __shared__ u16 tile[64][65];
  int tc = blockIdx.x * 64, tr = blockIdx.y * 64;
  int t = threadIdx.x;
  int rr = t >> 3;
  int c8 = (t & 7) * 8;
#pragma unroll
  for (int i = 0; i < 2; ++i) {
    int r = rr + i * 32;
    f32x4 p0 = *(const f32x4*)(src + (long)(tr + r) * C + tc + c8);
    f32x4 p1 = *(const f32x4*)(src + (long)(tr + r) * C + tc + c8 + 4);
#pragma unroll
    for (int j = 0; j < 4; ++j) {
      tile[r][c8 + j] = f2b(p0[j]);
      tile[r][c8 + 4 + j] = f2b(p1[j]);
    }
  }
  __syncthreads();
#pragma unroll
  for (int i = 0; i < 2; ++i) {
    int a = rr + i * 32;
    u16 vv[8];
#pragma unroll
    for (int j = 0; j < 8; ++j) vv[j] = tile[c8 + j][a];
    *(uint4*)(dst + (long)(tc + a) * R + tr + c8) = *(uint4*)vv;
  }
}

// ---------------- transpose bf16 src[R][C] -> bf16 dst[C][R], batched via z
__global__ __launch_bounds__(256) void transpose_b_k(const u16* __restrict__ src,
                                                     u16* __restrict__ dst,
                                                     int R, int C,
                                                     long sBatch, long dBatch) {
  __shared__ u16 tile[64][65];
  src += (long)blockIdx.z * sBatch;
  dst += (long)blockIdx.z * dBatch;
  int tc = blockIdx.x * 64, tr = blockIdx.y * 64;
  int t = threadIdx.x;
  int rr = t >> 3;
  int c8 = (t & 7) * 8;
#pragma unroll
  for (int i = 0; i < 2; ++i) {
    int r = rr + i * 32;
    uint4 v = *(const uint4*)(src + (long)(tr + r) * C + tc + c8);
    u16 vv[8]; *(uint4*)vv = v;
#pragma unroll
    for (int j = 0; j < 8; ++j) tile[r][c8 + j] = vv[j];
  }
  __syncthreads();
#pragma unroll
  for (int i = 0; i < 2; ++i) {
    int a = rr + i * 32;
    u16 vv[8];
#pragma unroll
    for (int j = 0; j < 8; ++j) vv[j] = tile[c8 + j][a];
    *(uint4*)(dst + (long)(tc + a) * R + tr + c8) = *(uint4*)vv;
  }
}

// ---------------- rope table: [2048][16] float2(cos,sin)
__global__ void rope_table_k(float2* __restrict__ tab) {
  int i = blockIdx.x * 256 + threadIdx.x;
  if (i >= 2048 * 16) return;
  int t = i >> 4, f = i & 15;
  float invf = exp2f(-(float)f * (13.287712379549449f / 16.0f));
  float th = (float)t * invf;
  float s, c;
  sincosf(th, &s, &c);
  tab[i] = make_float2(c, s);
}

// ---------------- QKV GEMM: qkv = x @ WaT^T + ba, RoPE fused in epilogue.
// R6-exact version (proven passing — FROZEN).
__global__ __launch_bounds__(256) void gemm_qkv_k(const float* __restrict__ A,
                                                  const u16* __restrict__ Bt,
                                                  const float* __restrict__ bias,
                                                  const float2* __restrict__ tab,
                                                  u16* __restrict__ out,
                                                  int M, int N, int K) {
  __shared__ u16 As[128 * 40];
  __shared__ u16 Bs[128 * 40];
  int tid = threadIdx.x, wid = tid >> 6, lane = tid & 63;
  int wr = wid >> 1, wc = wid & 1;
  long m0 = (long)blockIdx.x * 128, n0 = (long)blockIdx.y * 128;
  int r = lane & 15, g = lane >> 4;
  long arow = m0 + wid * 32 + (lane >> 2);
  int acol = (lane & 3) * 8;
  const float* Agf = A + arow * (long)K + acol;
  const u16* Bg = Bt + (n0 + wid * 32 + (lane >> 2)) * (long)K + acol;
  int lrow = wid * 32 + (lane >> 2);
  int lcol = acol;
  f32x4 acc[4][4] = {};
  int nk = K >> 5;
  for (int kt = 0; kt < nk; ++kt) {
    long ko = (long)kt * 32;
    f32x4 p0 = *(const f32x4*)(Agf + ko);
    f32x4 p1 = *(const f32x4*)(Agf + ko + 4);
    f32x4 p2 = *(const f32x4*)(Agf + ko + 16 * (long)K);
    f32x4 p3 = *(const f32x4*)(Agf + ko + 16 * (long)K + 4);
    u16 h0[8], h1[8];
#pragma unroll
    for (int j = 0; j < 4; ++j) {
      h0[j] = f2b(p0[j]); h0[4 + j] = f2b(p1[j]);
      h1[j] = f2b(p2[j]); h1[4 + j] = f2b(p3[j]);
    }
    uint4 a0 = *(uint4*)h0, a1 = *(uint4*)h1;
    uint4 b0 = *(const uint4*)(Bg + ko);
    uint4 b1 = *(const uint4*)(Bg + ko + 16 * (long)K);
    __syncthreads();
    *(uint4*)&As[lrow * 40 + lcol] = a0;
    *(uint4*)&As[(lrow + 16) * 40 + lcol] = a1;
    *(uint4*)&Bs[lrow * 40 + lcol] = b0;
    *(uint4*)&Bs[(lrow + 16) * 40 + lcol] = b1;
    __syncthreads();
    bf16x8 af[4], bfr[4];
#pragma unroll
    for (int mt = 0; mt < 4; ++mt)
      af[mt] = *(const bf16x8*)&As[(wr * 64 + mt * 16 + r) * 40 + g * 8];
#pragma unroll
    for (int nt = 0; nt < 4; ++nt)
      bfr[nt] = *(const bf16x8*)&Bs[(wc * 64 + nt * 16 + r) * 40 + g * 8];
#pragma unroll
    for (int mt = 0; mt < 4; ++mt)
#pragma unroll
      for (int nt = 0; nt < 4; ++nt)
        acc[mt][nt] = __builtin_amdgcn_mfma_f32_16x16x32_bf16(af[mt], bfr[nt], acc[mt][nt], 0, 0, 0);
  }
  int which = (int)(n0 >> 10);
  int hh = ((int)(n0 & 1023) >> 6) + wc;
  float bv[4];
#pragma unroll
  for (int nt = 0; nt < 4; ++nt) bv[nt] = bias[n0 + wc * 64 + nt * 16 + r];
#pragma unroll
  for (int mt = 0; mt < 4; ++mt) {
#pragma unroll
    for (int e = 0; e < 4; ++e) {
      long row = m0 + wr * 64 + mt * 16 + g * 4 + e;
      long bb = row >> 11;
      int tt = (int)row & 2047;
      float v0 = acc[mt][0][e] + bv[0];
      float v1 = acc[mt][1][e] + bv[1];
      float v2 = acc[mt][2][e] + bv[2];
      float v3 = acc[mt][3][e] + bv[3];
      if (which < 2) {
        float2 cs = tab[tt * 16 + r];
        float r0 = v0 * cs.x - v2 * cs.y, r2 = v2 * cs.x + v0 * cs.y;
        float r1 = v1 * cs.x - v3 * cs.y, r3 = v3 * cs.x + v1 * cs.y;
        if (which == 0) { r0 *= QSCALE; r1 *= QSCALE; r2 *= QSCALE; r3 *= QSCALE; }
        v0 = r0; v1 = r1; v2 = r2; v3 = r3;
      }
      u16* op = out + (long)which * 8388608 + (((bb * 16 + hh) * 2048 + tt) << 6);
      op[r] = f2b(v0);
      op[16 + r] = f2b(v1);
      op[32 + r] = f2b(v2);
      op[48 + r] = f2b(v3);
    }
  }
}

// ---------------- proj GEMM: out = A @ Bt^T + bias, global_load_lds staging.
__global__ __launch_bounds__(256) void gemm_proj_k(const u16* __restrict__ A,
                                                   const u16* __restrict__ Bt,
                                                   const float* __restrict__ bias,
                                                   float* __restrict__ out,
                                                   int M, int N, int K) {
  __shared__ u16 As[128 * 32];
  __shared__ u16 Bs[128 * 32];
  int tid = threadIdx.x, wid = tid >> 6, lane = tid & 63;
  int wr = wid >> 1, wc = wid & 1;
  long m0 = (long)blockIdx.x * 128, n0 = (long)blockIdx.y * 128;
  int r = lane & 15, g = lane >> 4;
  const u16* Ag = A + (m0 + wid * 32 + (lane >> 2)) * (long)K + (lane & 3) * 8;
  const u16* Bg = Bt + (n0 + wid * 32 + (lane >> 2)) * (long)K + (lane & 3) * 8;
  u16* AsW = As + wid * 1024;
  u16* BsW = Bs + wid * 1024;
  f32x4 acc[4][4] = {};
  int nk = K >> 5;
  for (int kt = 0; kt < nk; ++kt) {
    long ko = (long)kt * 32;
    GLOAD16(Ag + ko, AsW);
    GLOAD16(Ag + ko + 16 * (long)K, AsW + 512);
    GLOAD16(Bg + ko, BsW);
    GLOAD16(Bg + ko + 16 * (long)K, BsW + 512);
    __syncthreads();
    bf16x8 af[4], bfr[4];
#pragma unroll
    for (int mt = 0; mt < 4; ++mt)
      af[mt] = *(const bf16x8*)&As[(wr * 64 + mt * 16 + r) * 32 + g * 8];
#pragma unroll
    for (int nt = 0; nt < 4; ++nt)
      bfr[nt] = *(const bf16x8*)&Bs[(wc * 64 + nt * 16 + r) * 32 + g * 8];
#pragma unroll
    for (int mt = 0; mt < 4; ++mt)
#pragma unroll
      for (int nt = 0; nt < 4; ++nt)
        acc[mt][nt] = __builtin_amdgcn_mfma_f32_16x16x32_bf16(af[mt], bfr[nt], acc[mt][nt], 0, 0, 0);
    __syncthreads();
  }
#pragma unroll
  for (int nt = 0; nt < 4; ++nt) {
    long col = n0 + wc * 64 + nt * 16 + r;
    float bvv = bias[col];
#pragma unroll
    for (int mt = 0; mt < 4; ++mt)
#pragma unroll
      for (int e = 0; e < 4; ++e) {
        long row = m0 + wr * 64 + mt * 16 + g * 4 + e;
        out[row * N + col] = acc[mt][nt][e] + bvv;
      }
  }
}

// ======== attn helpers ========
__device__ __forceinline__ void pk_exchange(const f32x16& p, bf16x8& af0, bf16x8& af1) {
  unsigned w0, w1, w2, w3, w4, w5, w6, w7;
  asm("v_cvt_pk_bf16_f32 %0, %1, %2" : "=v"(w0) : "v"(p[0]), "v"(p[1]));
  asm("v_cvt_pk_bf16_f32 %0, %1, %2" : "=v"(w1) : "v"(p[2]), "v"(p[3]));
  asm("v_cvt_pk_bf16_f32 %0, %1, %2" : "=v"(w2) : "v"(p[4]), "v"(p[5]));
  asm("v_cvt_pk_bf16_f32 %0, %1, %2" : "=v"(w3) : "v"(p[6]), "v"(p[7]));
  asm("v_cvt_pk_bf16_f32 %0, %1, %2" : "=v"(w4) : "v"(p[8]), "v"(p[9]));
  asm("v_cvt_pk_bf16_f32 %0, %1, %2" : "=v"(w5) : "v"(p[10]), "v"(p[11]));
  asm("v_cvt_pk_bf16_f32 %0, %1, %2" : "=v"(w6) : "v"(p[12]), "v"(p[13]));
  asm("v_cvt_pk_bf16_f32 %0, %1, %2" : "=v"(w7) : "v"(p[14]), "v"(p[15]));
  asm("v_permlane32_swap_b32 %0, %1" : "+v"(w0), "+v"(w2));
  asm("v_permlane32_swap_b32 %0, %1" : "+v"(w1), "+v"(w3));
  asm("v_permlane32_swap_b32 %0, %1" : "+v"(w4), "+v"(w6));
  asm("v_permlane32_swap_b32 %0, %1" : "+v"(w5), "+v"(w7));
  union { unsigned u[4]; bf16x8 v; } c0, c1;
  c0.u[0] = w0; c0.u[1] = w1; c0.u[2] = w2; c0.u[3] = w3;
  c1.u[0] = w4; c1.u[1] = w5; c1.u[2] = w6; c1.u[3] = w7;
  af0 = c0.v;
  af1 = c1.v;
}

// ---------------- flash attention v10: 8-wave blocks, q-span 256, KVBLK=128.
// 2 kv sub-tiles per barrier pair (barrier count halved vs v9). Same R12-proven
// protocol: barrier -> LDS write -> barrier -> hoist next loads -> compute.
__global__ __launch_bounds__(512) void attn_k(const u16* __restrict__ Qg,
                                              const u16* __restrict__ Kg,
                                              const u16* __restrict__ VgT,
                                              u16* __restrict__ Y) {
  __shared__ u16 Ks[128 * 72];   // [kv 128][d 64] +8 pad
  __shared__ u16 Vt[64 * 136];   // [d 64][kv 128] +8 pad
  const int qmap[8] = {7, 5, 6, 4, 0, 2, 1, 3};  // pairs (y, y+4) sum to 7
  int qb = qmap[blockIdx.y];
  int bh = blockIdx.x;
  int b = bh >> 4, h = bh & 15;
  long base = (long)bh * (2048 * 64);
  int tid = threadIdx.x, wid = tid >> 6;       // 0..7
  int lane = tid & 63, l31 = lane & 31, hi = lane >> 5;
  int q0 = qb * 256 + wid * 32;
  int endS = (q0 + 31) >> 6;      // last kv tile for this wave
  int nIter = 2 * qb + 2;         // 128-wide iterations covering kt 0..4qb+3
  // staging: 512 threads x 2 uint4 per array (K: 128x64 u16, V: 64x128 u16)
  int kr = tid >> 3, kch = (tid & 7) * 8;
  const u16* kSrc0 = Kg + base + (long)kr * 64 + kch;        // +ktp*8192
  const u16* kSrc1 = kSrc0 + 64 * 64;                        // rows +64
  int sK0 = kr * 72 + kch, sK1 = sK0 + 64 * 72;
  int vr = tid >> 4, vch = (tid & 15) * 8;
  const u16* vSrc0 = VgT + base + (long)vr * 2048 + vch;     // +ktp*128
  const u16* vSrc1 = vSrc0 + 32 * 2048;                      // d rows +32
  int sV0 = vr * 136 + vch, sV1 = sV0 + 32 * 136;
  bf16x8 qf[4];
  {
    const u16* qp = Qg + base + (long)(q0 + l31) * 64 + hi * 8;
#pragma unroll
    for (int s4 = 0; s4 < 4; ++s4) qf[s4] = *(const bf16x8*)(qp + s4 * 16);
  }
  f32x16 acc0 = {}, acc1 = {};
  float mrow = -INFINITY, lrow = 0.f;
  // prologue: iteration-0 loads in flight
  uint4 rk0 = *(const uint4*)kSrc0;
  uint4 rk1 = *(const uint4*)kSrc1;
  uint4 rv0 = *(const uint4*)vSrc0;
  uint4 rv1 = *(const uint4*)vSrc1;
  for (int ktp = 0; ktp < nIter; ++ktp) {
    __syncthreads();            // all waves done reading previous LDS tile
    *(uint4*)&Ks[sK0] = rk0;
    *(uint4*)&Ks[sK1] = rk1;
    *(uint4*)&Vt[sV0] = rv0;
    *(uint4*)&Vt[sV1] = rv1;
    __syncthreads();            // tile pair visible
    if (ktp + 1 < nIter) {      // hoist next-iteration loads under this compute
      long ko = (long)(ktp + 1) * 8192;
      long vo = (long)(ktp + 1) * 128;
      rk0 = *(const uint4*)(kSrc0 + ko);
      rk1 = *(const uint4*)(kSrc1 + ko);
      rv0 = *(const uint4*)(vSrc0 + vo);
      rv1 = *(const uint4*)(vSrc1 + vo);
    }
#pragma unroll
    for (int sub = 0; sub < 2; ++sub) {
      int kt = ktp * 2 + sub;
      if (kt > endS) continue;  // wave done with its strip (still hits barriers)
      f32x16 st[2];
      __builtin_amdgcn_s_setprio(1);
#pragma unroll
      for (int ct = 0; ct < 2; ++ct) {
        f32x16 z = {};
#pragma unroll
        for (int s4 = 0; s4 < 4; ++s4) {
          bf16x8 kf = *(const bf16x8*)&Ks[(sub * 64 + ct * 32 + l31) * 72 + s4 * 16 + hi * 8];
          z = __builtin_amdgcn_mfma_f32_32x32x16_bf16(kf, qf[s4], z, 0, 0, 0);
        }
        st[ct] = z;
      }
      __builtin_amdgcn_s_setprio(0);
      if (kt == endS) {  // causal mask on diagonal tile
        int qg = q0 + l31;
#pragma unroll
        for (int ct = 0; ct < 2; ++ct)
#pragma unroll
          for (int reg = 0; reg < 16; ++reg) {
            int kg = kt * 64 + ct * 32 + (reg & 3) + 8 * (reg >> 2) + 4 * hi;
            if (kg > qg) st[ct][reg] = -INFINITY;
          }
      }
      float t8[8];
#pragma unroll
      for (int i = 0; i < 8; ++i)
        t8[i] = fmaxf(fmaxf(st[0][i], st[0][i + 8]), fmaxf(st[1][i], st[1][i + 8]));
#pragma unroll
      for (int i = 0; i < 4; ++i) t8[i] = fmaxf(t8[i], t8[i + 4]);
      float pm = fmaxf(fmaxf(t8[0], t8[1]), fmaxf(t8[2], t8[3]));
      pm = fmaxf(pm, __shfl_xor(pm, 32));
      if (__any(pm > mrow + 8.0f)) {  // defer-max (T13)
        float mn = fmaxf(mrow, pm);
        float alpha = exp2f(mrow - mn);
        mrow = mn;
        lrow *= alpha;
#pragma unroll
        for (int reg = 0; reg < 16; ++reg) {
          float aB = __shfl(alpha, (reg & 3) + 8 * (reg >> 2) + 4 * hi);
          acc0[reg] *= aB;
          acc1[reg] *= aB;
        }
      }
      float s8[8];
#pragma unroll
      for (int i = 0; i < 8; ++i) s8[i] = 0.f;
#pragma unroll
      for (int ct = 0; ct < 2; ++ct)
#pragma unroll
        for (int reg = 0; reg < 16; ++reg) {
          float p = exp2f(st[ct][reg] - mrow);
          st[ct][reg] = p;
          s8[reg & 7] += p;
        }
#pragma unroll
      for (int i = 0; i < 4; ++i) s8[i] += s8[i + 4];
      float rs = (s8[0] + s8[1]) + (s8[2] + s8[3]);
      rs += __shfl_xor(rs, 32);
      lrow += rs;
#pragma unroll
      for (int ct = 0; ct < 2; ++ct) {
        bf16x8 af[2];
        pk_exchange(st[ct], af[0], af[1]);
        __builtin_amdgcn_s_setprio(1);
#pragma unroll
        for (int ks = 0; ks < 2; ++ks) {
          bf16x8 vf0 = *(const bf16x8*)&Vt[l31 * 136 + sub * 64 + ct * 32 + ks * 16 + hi * 8];
          bf16x8 vf1 = *(const bf16x8*)&Vt[(32 + l31) * 136 + sub * 64 + ct * 32 + ks * 16 + hi * 8];
          acc0 = __builtin_amdgcn_mfma_f32_32x32x16_bf16(af[ks], vf0, acc0, 0, 0, 0);
          acc1 = __builtin_amdgcn_mfma_f32_32x32x16_bf16(af[ks], vf1, acc1, 0, 0, 0);
        }
        __builtin_amdgcn_s_setprio(0);
      }
    }
  }
  float rinv = 1.0f / lrow;
#pragma unroll
  for (int reg = 0; reg < 16; ++reg) {
    int crow = (reg & 3) + 8 * (reg >> 2) + 4 * hi;
    float rB = __shfl(rinv, crow);
    long orow = (long)(b * 2048 + q0 + crow) * 1024 + h * 64;
    Y[orow + l31] = f2b(acc0[reg] * rB);
    Y[orow + 32 + l31] = f2b(acc1[reg] * rB);
  }
}

extern "C" void kernel_launch(void* const* d_in, const int* in_sizes, int n_in,
                              void* d_out, int out_size, void* d_ws, size_t ws_size,
                              hipStream_t stream) {
  const float* x  = (const float*)d_in[0];
  const float* Wa = (const float*)d_in[1];
  const float* ba = (const float*)d_in[2];
  const float* Wp = (const float*)d_in[3];
  const float* bp = (const float*)d_in[4];

  if (ws_size < 67108864ULL) {
    sentinel_k<<<dim3((out_size + 255) / 256), 256, 0, stream>>>((u16*)d_out, out_size);
    return;
  }

  u16* ws  = (u16*)d_ws;
  u16* Qg  = ws;                           // [0, 8388608)
  u16* Kg  = ws + 8388608;                 // [8388608, 16777216)
  u16* Vg  = ws + 16777216;                // [16777216, 25165824)
  u16* Yb  = ws + 16777216;                // over dead Vg (after V-transpose)
  u16* WaT = ws + 25165824;                // bf16, dead after QKV GEMM
  float2* tab = (float2*)(ws + 28311552);  // dead after QKV GEMM
  u16* VgT = ws + 25165824;                // over dead WaT+tab
  u16* WpT = ws;                           // over dead Qg (after attn)

  transpose_f2b_k<<<dim3(48, 16), 256, 0, stream>>>(Wa, WaT, 1024, 3072);
  rope_table_k<<<dim3(128), 256, 0, stream>>>(tab);
  gemm_qkv_k<<<dim3(64, 24), 256, 0, stream>>>(x, WaT, ba, tab, Qg, 8192, 3072, 1024);
  transpose_b_k<<<dim3(1, 32, 64), 256, 0, stream>>>(Vg, VgT, 2048, 64, 131072L, 131072L);
  attn_k<<<dim3(64, 8), 512, 0, stream>>>(Qg, Kg, VgT, Yb);
  transpose_f2b_k<<<dim3(16, 16), 256, 0, stream>>>(Wp, WpT, 1024, 1024);
  gemm_proj_k<<<dim3(64, 8), 256, 0, stream>>>(Yb, WpT, bp, (float*)d_out, 8192, 1024, 1024);
}

// Round 19
// 198.263 us; speedup vs baseline: 1.3329x; 1.0979x over previous
//
#include <hip/hip_runtime.h>
#include <math.h>

// CausalSelfAttention: B=4 T=2048 C=1024 H=16 hd=64. fp32 I/O, bf16 MFMA internals.
// R18 = R15-exact (passed, 199.1us; R17's KVBLK=128 reverted — VGPR=68 spill) +
// ONE change: attn __launch_bounds__(512) -> (512, 2). Min 2 waves/EU => VGPR cap
// 256/wave: keeps the ~100-float working set in registers (R17 spilled at 68).
// gemm_qkv FROZEN at R6 staging (gload_lds+xcvt variants convicted R13/R14).
//
// ws (u16 elems), peak 33,554,432 u16 = 64 MiB:
//   [0,        8388608)  Qg          ... after attn: WpT over dead Qg
//   [8388608, 16777216)  Kg
//   [16777216,25165824)  Vg          ... after V-transpose: Yb over dead Vg
//   [25165824,28311552)  WaT (bf16)  ... dead after QKV GEMM
//   [28311552,28442624)  rope tab    ... dead after QKV GEMM
//   [25165824,33554432)  VgT (over dead WaT+tab)

typedef unsigned short u16;
typedef __bf16 bf16x8 __attribute__((ext_vector_type(8)));
typedef float f32x4 __attribute__((ext_vector_type(4)));
typedef float f32x16 __attribute__((ext_vector_type(16)));

#define QSCALE 0.18033688501389543f  // 0.125 * log2(e)

__device__ __forceinline__ float b2f(u16 x) {
  union { unsigned u; float f; } c; c.u = ((unsigned)x) << 16; return c.f;
}
__device__ __forceinline__ u16 f2b(float f) {
  union { __bf16 h; u16 u; } c; c.h = (__bf16)f; return c.u;
}

#define GLOAD16(gp, lp)                                                  \
  __builtin_amdgcn_global_load_lds(                                      \
      (const __attribute__((address_space(1))) unsigned int*)(gp),       \
      (__attribute__((address_space(3))) unsigned int*)(lp), 16, 0, 0)

// ---------------- sentinel fill (ws too small signal)
__global__ __launch_bounds__(256) void sentinel_k(u16* __restrict__ out, int n) {
  int i = blockIdx.x * 256 + threadIdx.x;
  if (i < n) out[i] = 0x4480;  // bf16 1024.0
}

// ---------------- transpose fp32 src[R][C] -> bf16 dst[C][R], 64x64 tiles
__global__ __launch_bounds__(256) void transpose_f2b_k(const float* __restrict__ src,
                                                       u16* __restrict__ dst,
                                                       int R, int C) {
  __shared__ u16 tile[64][65];
  int tc = blockIdx.x * 64, tr = blockIdx.y * 64;
  int t = threadIdx.x;
  int rr = t >> 3;
  int c8 = (t & 7) * 8;
#pragma unroll
  for (int i = 0; i < 2; ++i) {
    int r = rr + i * 32;
    f32x4 p0 = *(const f32x4*)(src + (long)(tr + r) * C + tc + c8);
    f32x4 p1 = *(const f32x4*)(src + (long)(tr + r) * C + tc + c8 + 4);
#pragma unroll
    for (int j = 0; j < 4; ++j) {
      tile[r][c8 + j] = f2b(p0[j]);
      tile[r][c8 + 4 + j] = f2b(p1[j]);
    }
  }
  __syncthreads();
#pragma unroll
  for (int i = 0; i < 2; ++i) {
    int a = rr + i * 32;
    u16 vv[8];
#pragma unroll
    for (int j = 0; j < 8; ++j) vv[j] = tile[c8 + j][a];
    *(uint4*)(dst + (long)(tc + a) * R + tr + c8) = *(uint4*)vv;
  }
}

// ---------------- transpose bf16 src[R][C] -> bf16 dst[C][R], batched via z
__global__ __launch_bounds__(256) void transpose_b_k(const u16* __restrict__ src,
                                                     u16* __restrict__ dst,
                                                     int R, int C,
                                                     long sBatch, long dBatch) {
  __shared__ u16 tile[64][65];
  src += (long)blockIdx.z * sBatch;
  dst += (long)blockIdx.z * dBatch;
  int tc = blockIdx.x * 64, tr = blockIdx.y * 64;
  int t = threadIdx.x;
  int rr = t >> 3;
  int c8 = (t & 7) * 8;
#pragma unroll
  for (int i = 0; i < 2; ++i) {
    int r = rr + i * 32;
    uint4 v = *(const uint4*)(src + (long)(tr + r) * C + tc + c8);
    u16 vv[8]; *(uint4*)vv = v;
#pragma unroll
    for (int j = 0; j < 8; ++j) tile[r][c8 + j] = vv[j];
  }
  __syncthreads();
#pragma unroll
  for (int i = 0; i < 2; ++i) {
    int a = rr + i * 32;
    u16 vv[8];
#pragma unroll
    for (int j = 0; j < 8; ++j) vv[j] = tile[c8 + j][a];
    *(uint4*)(dst + (long)(tc + a) * R + tr + c8) = *(uint4*)vv;
  }
}

// ---------------- rope table: [2048][16] float2(cos,sin)
__global__ void rope_table_k(float2* __restrict__ tab) {
  int i = blockIdx.x * 256 + threadIdx.x;
  if (i >= 2048 * 16) return;
  int t = i >> 4, f = i & 15;
  float invf = exp2f(-(float)f * (13.287712379549449f / 16.0f));
  float th = (float)t * invf;
  float s, c;
  sincosf(th, &s, &c);
  tab[i] = make_float2(c, s);
}

// ---------------- QKV GEMM: qkv = x @ WaT^T + ba, RoPE fused in epilogue.
// R6-exact version (proven passing — FROZEN).
__global__ __launch_bounds__(256) void gemm_qkv_k(const float* __restrict__ A,
                                                  const u16* __restrict__ Bt,
                                                  const float* __restrict__ bias,
                                                  const float2* __restrict__ tab,
                                                  u16* __restrict__ out,
                                                  int M, int N, int K) {
  __shared__ u16 As[128 * 40];
  __shared__ u16 Bs[128 * 40];
  int tid = threadIdx.x, wid = tid >> 6, lane = tid & 63;
  int wr = wid >> 1, wc = wid & 1;
  long m0 = (long)blockIdx.x * 128, n0 = (long)blockIdx.y * 128;
  int r = lane & 15, g = lane >> 4;
  long arow = m0 + wid * 32 + (lane >> 2);
  int acol = (lane & 3) * 8;
  const float* Agf = A + arow * (long)K + acol;
  const u16* Bg = Bt + (n0 + wid * 32 + (lane >> 2)) * (long)K + acol;
  int lrow = wid * 32 + (lane >> 2);
  int lcol = acol;
  f32x4 acc[4][4] = {};
  int nk = K >> 5;
  for (int kt = 0; kt < nk; ++kt) {
    long ko = (long)kt * 32;
    f32x4 p0 = *(const f32x4*)(Agf + ko);
    f32x4 p1 = *(const f32x4*)(Agf + ko + 4);
    f32x4 p2 = *(const f32x4*)(Agf + ko + 16 * (long)K);
    f32x4 p3 = *(const f32x4*)(Agf + ko + 16 * (long)K + 4);
    u16 h0[8], h1[8];
#pragma unroll
    for (int j = 0; j < 4; ++j) {
      h0[j] = f2b(p0[j]); h0[4 + j] = f2b(p1[j]);
      h1[j] = f2b(p2[j]); h1[4 + j] = f2b(p3[j]);
    }
    uint4 a0 = *(uint4*)h0, a1 = *(uint4*)h1;
    uint4 b0 = *(const uint4*)(Bg + ko);
    uint4 b1 = *(const uint4*)(Bg + ko + 16 * (long)K);
    __syncthreads();
    *(uint4*)&As[lrow * 40 + lcol] = a0;
    *(uint4*)&As[(lrow + 16) * 40 + lcol] = a1;
    *(uint4*)&Bs[lrow * 40 + lcol] = b0;
    *(uint4*)&Bs[(lrow + 16) * 40 + lcol] = b1;
    __syncthreads();
    bf16x8 af[4], bfr[4];
#pragma unroll
    for (int mt = 0; mt < 4; ++mt)
      af[mt] = *(const bf16x8*)&As[(wr * 64 + mt * 16 + r) * 40 + g * 8];
#pragma unroll
    for (int nt = 0; nt < 4; ++nt)
      bfr[nt] = *(const bf16x8*)&Bs[(wc * 64 + nt * 16 + r) * 40 + g * 8];
#pragma unroll
    for (int mt = 0; mt < 4; ++mt)
#pragma unroll
      for (int nt = 0; nt < 4; ++nt)
        acc[mt][nt] = __builtin_amdgcn_mfma_f32_16x16x32_bf16(af[mt], bfr[nt], acc[mt][nt], 0, 0, 0);
  }
  int which = (int)(n0 >> 10);
  int hh = ((int)(n0 & 1023) >> 6) + wc;
  float bv[4];
#pragma unroll
  for (int nt = 0; nt < 4; ++nt) bv[nt] = bias[n0 + wc * 64 + nt * 16 + r];
#pragma unroll
  for (int mt = 0; mt < 4; ++mt) {
#pragma unroll
    for (int e = 0; e < 4; ++e) {
      long row = m0 + wr * 64 + mt * 16 + g * 4 + e;
      long bb = row >> 11;
      int tt = (int)row & 2047;
      float v0 = acc[mt][0][e] + bv[0];
      float v1 = acc[mt][1][e] + bv[1];
      float v2 = acc[mt][2][e] + bv[2];
      float v3 = acc[mt][3][e] + bv[3];
      if (which < 2) {
        float2 cs = tab[tt * 16 + r];
        float r0 = v0 * cs.x - v2 * cs.y, r2 = v2 * cs.x + v0 * cs.y;
        float r1 = v1 * cs.x - v3 * cs.y, r3 = v3 * cs.x + v1 * cs.y;
        if (which == 0) { r0 *= QSCALE; r1 *= QSCALE; r2 *= QSCALE; r3 *= QSCALE; }
        v0 = r0; v1 = r1; v2 = r2; v3 = r3;
      }
      u16* op = out + (long)which * 8388608 + (((bb * 16 + hh) * 2048 + tt) << 6);
      op[r] = f2b(v0);
      op[16 + r] = f2b(v1);
      op[32 + r] = f2b(v2);
      op[48 + r] = f2b(v3);
    }
  }
}

// ---------------- proj GEMM: out = A @ Bt^T + bias, global_load_lds staging.
__global__ __launch_bounds__(256) void gemm_proj_k(const u16* __restrict__ A,
                                                   const u16* __restrict__ Bt,
                                                   const float* __restrict__ bias,
                                                   float* __restrict__ out,
                                                   int M, int N, int K) {
  __shared__ u16 As[128 * 32];
  __shared__ u16 Bs[128 * 32];
  int tid = threadIdx.x, wid = tid >> 6, lane = tid & 63;
  int wr = wid >> 1, wc = wid & 1;
  long m0 = (long)blockIdx.x * 128, n0 = (long)blockIdx.y * 128;
  int r = lane & 15, g = lane >> 4;
  const u16* Ag = A + (m0 + wid * 32 + (lane >> 2)) * (long)K + (lane & 3) * 8;
  const u16* Bg = Bt + (n0 + wid * 32 + (lane >> 2)) * (long)K + (lane & 3) * 8;
  u16* AsW = As + wid * 1024;
  u16* BsW = Bs + wid * 1024;
  f32x4 acc[4][4] = {};
  int nk = K >> 5;
  for (int kt = 0; kt < nk; ++kt) {
    long ko = (long)kt * 32;
    GLOAD16(Ag + ko, AsW);
    GLOAD16(Ag + ko + 16 * (long)K, AsW + 512);
    GLOAD16(Bg + ko, BsW);
    GLOAD16(Bg + ko + 16 * (long)K, BsW + 512);
    __syncthreads();
    bf16x8 af[4], bfr[4];
#pragma unroll
    for (int mt = 0; mt < 4; ++mt)
      af[mt] = *(const bf16x8*)&As[(wr * 64 + mt * 16 + r) * 32 + g * 8];
#pragma unroll
    for (int nt = 0; nt < 4; ++nt)
      bfr[nt] = *(const bf16x8*)&Bs[(wc * 64 + nt * 16 + r) * 32 + g * 8];
#pragma unroll
    for (int mt = 0; mt < 4; ++mt)
#pragma unroll
      for (int nt = 0; nt < 4; ++nt)
        acc[mt][nt] = __builtin_amdgcn_mfma_f32_16x16x32_bf16(af[mt], bfr[nt], acc[mt][nt], 0, 0, 0);
    __syncthreads();
  }
#pragma unroll
  for (int nt = 0; nt < 4; ++nt) {
    long col = n0 + wc * 64 + nt * 16 + r;
    float bvv = bias[col];
#pragma unroll
    for (int mt = 0; mt < 4; ++mt)
#pragma unroll
      for (int e = 0; e < 4; ++e) {
        long row = m0 + wr * 64 + mt * 16 + g * 4 + e;
        out[row * N + col] = acc[mt][nt][e] + bvv;
      }
  }
}

// ======== attn helpers ========
__device__ __forceinline__ void pk_exchange(const f32x16& p, bf16x8& af0, bf16x8& af1) {
  unsigned w0, w1, w2, w3, w4, w5, w6, w7;
  asm("v_cvt_pk_bf16_f32 %0, %1, %2" : "=v"(w0) : "v"(p[0]), "v"(p[1]));
  asm("v_cvt_pk_bf16_f32 %0, %1, %2" : "=v"(w1) : "v"(p[2]), "v"(p[3]));
  asm("v_cvt_pk_bf16_f32 %0, %1, %2" : "=v"(w2) : "v"(p[4]), "v"(p[5]));
  asm("v_cvt_pk_bf16_f32 %0, %1, %2" : "=v"(w3) : "v"(p[6]), "v"(p[7]));
  asm("v_cvt_pk_bf16_f32 %0, %1, %2" : "=v"(w4) : "v"(p[8]), "v"(p[9]));
  asm("v_cvt_pk_bf16_f32 %0, %1, %2" : "=v"(w5) : "v"(p[10]), "v"(p[11]));
  asm("v_cvt_pk_bf16_f32 %0, %1, %2" : "=v"(w6) : "v"(p[12]), "v"(p[13]));
  asm("v_cvt_pk_bf16_f32 %0, %1, %2" : "=v"(w7) : "v"(p[14]), "v"(p[15]));
  asm("v_permlane32_swap_b32 %0, %1" : "+v"(w0), "+v"(w2));
  asm("v_permlane32_swap_b32 %0, %1" : "+v"(w1), "+v"(w3));
  asm("v_permlane32_swap_b32 %0, %1" : "+v"(w4), "+v"(w6));
  asm("v_permlane32_swap_b32 %0, %1" : "+v"(w5), "+v"(w7));
  union { unsigned u[4]; bf16x8 v; } c0, c1;
  c0.u[0] = w0; c0.u[1] = w1; c0.u[2] = w2; c0.u[3] = w3;
  c1.u[0] = w4; c1.u[1] = w5; c1.u[2] = w6; c1.u[3] = w7;
  af0 = c0.v;
  af1 = c1.v;
}

// ---------------- flash attention v9b: 8-wave blocks, q-span 256, KVBLK=64.
// R15-exact body; __launch_bounds__(512,2) lifts the VGPR cap (no spill).
__global__ __launch_bounds__(512, 2) void attn_k(const u16* __restrict__ Qg,
                                                 const u16* __restrict__ Kg,
                                                 const u16* __restrict__ VgT,
                                                 u16* __restrict__ Y) {
  __shared__ u16 Ks[64 * 72];  // [kv 64][d 64] +8 pad
  __shared__ u16 Vt[64 * 72];  // [d 64][kv 64] +8 pad
  const int qmap[8] = {7, 5, 6, 4, 0, 2, 1, 3};  // pairs (y, y+4) sum to 7
  int qb = qmap[blockIdx.y];
  int bh = blockIdx.x;
  int b = bh >> 4, h = bh & 15;
  long base = (long)bh * (2048 * 64);
  int tid = threadIdx.x, wid = tid >> 6;       // 0..7
  int lane = tid & 63, l31 = lane & 31, hi = lane >> 5;
  int q0 = qb * 256 + wid * 32;
  int endS = (q0 + 31) >> 6;    // last kv tile for this wave
  int ktMax = 4 * qb + 3;       // block max (wave 7)
  // staging: 512 threads x 1 uint4 = 64x64 u16 per array
  int srow = tid >> 3, sch = (tid & 7) * 8;
  const u16* kSrc = Kg + base + (long)srow * 64 + sch;     // +kt*4096
  const u16* vSrc = VgT + base + (long)srow * 2048 + sch;  // +kt*64
  int sOff = srow * 72 + sch;
  bf16x8 qf[4];
  {
    const u16* qp = Qg + base + (long)(q0 + l31) * 64 + hi * 8;
#pragma unroll
    for (int s4 = 0; s4 < 4; ++s4) qf[s4] = *(const bf16x8*)(qp + s4 * 16);
  }
  f32x16 acc0 = {}, acc1 = {};
  float mrow = -INFINITY, lrow = 0.f;
  // prologue: tile-0 loads in flight
  uint4 rk = *(const uint4*)kSrc;
  uint4 rv = *(const uint4*)vSrc;
  for (int kt = 0; kt <= ktMax; ++kt) {
    __syncthreads();            // all waves done reading tile kt-1
    *(uint4*)&Ks[sOff] = rk;
    *(uint4*)&Vt[sOff] = rv;
    __syncthreads();            // tile kt visible
    if (kt < ktMax) {           // hoist tile kt+1 loads under this compute
      rk = *(const uint4*)(kSrc + (long)(kt + 1) * 4096);
      rv = *(const uint4*)(vSrc + (long)(kt + 1) * 64);
    }
    if (kt > endS) continue;    // wave done with its strip (still hits barriers)
    f32x16 st[2];
    __builtin_amdgcn_s_setprio(1);
#pragma unroll
    for (int ct = 0; ct < 2; ++ct) {
      f32x16 z = {};
#pragma unroll
      for (int s4 = 0; s4 < 4; ++s4) {
        bf16x8 kf = *(const bf16x8*)&Ks[(ct * 32 + l31) * 72 + s4 * 16 + hi * 8];
        z = __builtin_amdgcn_mfma_f32_32x32x16_bf16(kf, qf[s4], z, 0, 0, 0);
      }
      st[ct] = z;
    }
    __builtin_amdgcn_s_setprio(0);
    if (kt == endS) {  // causal mask on diagonal tile
      int qg = q0 + l31;
#pragma unroll
      for (int ct = 0; ct < 2; ++ct)
#pragma unroll
        for (int reg = 0; reg < 16; ++reg) {
          int kg = kt * 64 + ct * 32 + (reg & 3) + 8 * (reg >> 2) + 4 * hi;
          if (kg > qg) st[ct][reg] = -INFINITY;
        }
    }
    float t8[8];
#pragma unroll
    for (int i = 0; i < 8; ++i)
      t8[i] = fmaxf(fmaxf(st[0][i], st[0][i + 8]), fmaxf(st[1][i], st[1][i + 8]));
#pragma unroll
    for (int i = 0; i < 4; ++i) t8[i] = fmaxf(t8[i], t8[i + 4]);
    float pm = fmaxf(fmaxf(t8[0], t8[1]), fmaxf(t8[2], t8[3]));
    pm = fmaxf(pm, __shfl_xor(pm, 32));
    if (__any(pm > mrow + 8.0f)) {  // defer-max (T13)
      float mn = fmaxf(mrow, pm);
      float alpha = exp2f(mrow - mn);
      mrow = mn;
      lrow *= alpha;
#pragma unroll
      for (int reg = 0; reg < 16; ++reg) {
        float aB = __shfl(alpha, (reg & 3) + 8 * (reg >> 2) + 4 * hi);
        acc0[reg] *= aB;
        acc1[reg] *= aB;
      }
    }
    float s8[8];
#pragma unroll
    for (int i = 0; i < 8; ++i) s8[i] = 0.f;
#pragma unroll
    for (int ct = 0; ct < 2; ++ct)
#pragma unroll
      for (int reg = 0; reg < 16; ++reg) {
        float p = exp2f(st[ct][reg] - mrow);
        st[ct][reg] = p;
        s8[reg & 7] += p;
      }
#pragma unroll
    for (int i = 0; i < 4; ++i) s8[i] += s8[i + 4];
    float rs = (s8[0] + s8[1]) + (s8[2] + s8[3]);
    rs += __shfl_xor(rs, 32);
    lrow += rs;
#pragma unroll
    for (int ct = 0; ct < 2; ++ct) {
      bf16x8 af[2];
      pk_exchange(st[ct], af[0], af[1]);
      __builtin_amdgcn_s_setprio(1);
#pragma unroll
      for (int ks = 0; ks < 2; ++ks) {
        bf16x8 vf0 = *(const bf16x8*)&Vt[l31 * 72 + ct * 32 + ks * 16 + hi * 8];
        bf16x8 vf1 = *(const bf16x8*)&Vt[(32 + l31) * 72 + ct * 32 + ks * 16 + hi * 8];
        acc0 = __builtin_amdgcn_mfma_f32_32x32x16_bf16(af[ks], vf0, acc0, 0, 0, 0);
        acc1 = __builtin_amdgcn_mfma_f32_32x32x16_bf16(af[ks], vf1, acc1, 0, 0, 0);
      }
      __builtin_amdgcn_s_setprio(0);
    }
  }
  float rinv = 1.0f / lrow;
#pragma unroll
  for (int reg = 0; reg < 16; ++reg) {
    int crow = (reg & 3) + 8 * (reg >> 2) + 4 * hi;
    float rB = __shfl(rinv, crow);
    long orow = (long)(b * 2048 + q0 + crow) * 1024 + h * 64;
    Y[orow + l31] = f2b(acc0[reg] * rB);
    Y[orow + 32 + l31] = f2b(acc1[reg] * rB);
  }
}

extern "C" void kernel_launch(void* const* d_in, const int* in_sizes, int n_in,
                              void* d_out, int out_size, void* d_ws, size_t ws_size,
                              hipStream_t stream) {
  const float* x  = (const float*)d_in[0];
  const float* Wa = (const float*)d_in[1];
  const float* ba = (const float*)d_in[2];
  const float* Wp = (const float*)d_in[3];
  const float* bp = (const float*)d_in[4];

  if (ws_size < 67108864ULL) {
    sentinel_k<<<dim3((out_size + 255) / 256), 256, 0, stream>>>((u16*)d_out, out_size);
    return;
  }

  u16* ws  = (u16*)d_ws;
  u16* Qg  = ws;                           // [0, 8388608)
  u16* Kg  = ws + 8388608;                 // [8388608, 16777216)
  u16* Vg  = ws + 16777216;                // [16777216, 25165824)
  u16* Yb  = ws + 16777216;                // over dead Vg (after V-transpose)
  u16* WaT = ws + 25165824;                // bf16, dead after QKV GEMM
  float2* tab = (float2*)(ws + 28311552);  // dead after QKV GEMM
  u16* VgT = ws + 25165824;                // over dead WaT+tab
  u16* WpT = ws;                           // over dead Qg (after attn)

  transpose_f2b_k<<<dim3(48, 16), 256, 0, stream>>>(Wa, WaT, 1024, 3072);
  rope_table_k<<<dim3(128), 256, 0, stream>>>(tab);
  gemm_qkv_k<<<dim3(64, 24), 256, 0, stream>>>(x, WaT, ba, tab, Qg, 8192, 3072, 1024);
  transpose_b_k<<<dim3(1, 32, 64), 256, 0, stream>>>(Vg, VgT, 2048, 64, 131072L, 131072L);
  attn_k<<<dim3(64, 8), 512, 0, stream>>>(Qg, Kg, VgT, Yb);
  transpose_f2b_k<<<dim3(16, 16), 256, 0, stream>>>(Wp, WpT, 1024, 1024);
  gemm_proj_k<<<dim3(64, 8), 256, 0, stream>>>(Yb, WpT, bp, (float*)d_out, 8192, 1024, 1024);
}